// Round 1
// baseline (1506.433 us; speedup 1.0000x reference)
//
#include <hip/hip_runtime.h>
#include <math.h>

// ---------------------------------------------------------------------------
// Decoder block: B=2, S=2048, D=512, H=8, DK=64, FF=2048.  All fp32.
// scores = floor(qk/8); masks are dead (reference bug replicated: no mask).
// ---------------------------------------------------------------------------

// ---------------- GEMM: C[M,N] = A[M,K] @ W[K,N] + bias, optional ReLU -----
__global__ __launch_bounds__(256) void gemm_bias_kernel(
    const float* __restrict__ A, const float* __restrict__ W,
    const float* __restrict__ bias, float* __restrict__ C,
    int M, int N, int K, int relu)
{
    __shared__ float As[16][64];   // [k][m]
    __shared__ float Bs[16][64];   // [k][n]
    const int tid = threadIdx.x;
    const int tx = tid & 15, ty = tid >> 4;
    const int bm = blockIdx.y * 64, bn = blockIdx.x * 64;

    // load indices
    const int arow = tid >> 2, akk = (tid & 3) * 4;   // A: 64 rows x 16 k
    const int brow = tid >> 4, bnn = (tid & 15) * 4;  // B: 16 rows x 64 n

    float c[4][4] = {};
    for (int k0 = 0; k0 < K; k0 += 16) {
        float4 a4 = *(const float4*)(A + (size_t)(bm + arow) * K + (k0 + akk));
        float4 b4 = *(const float4*)(W + (size_t)(k0 + brow) * N + (bn + bnn));
        As[akk + 0][arow] = a4.x; As[akk + 1][arow] = a4.y;
        As[akk + 2][arow] = a4.z; As[akk + 3][arow] = a4.w;
        *(float4*)&Bs[brow][bnn] = b4;
        __syncthreads();
        #pragma unroll
        for (int kk = 0; kk < 16; ++kk) {
            float4 af = *(const float4*)&As[kk][ty * 4];
            float4 bf = *(const float4*)&Bs[kk][tx * 4];
            float a[4] = {af.x, af.y, af.z, af.w};
            float b[4] = {bf.x, bf.y, bf.z, bf.w};
            #pragma unroll
            for (int i = 0; i < 4; ++i)
                #pragma unroll
                for (int j = 0; j < 4; ++j)
                    c[i][j] = fmaf(a[i], b[j], c[i][j]);
        }
        __syncthreads();
    }
    const int m0 = bm + ty * 4, n0 = bn + tx * 4;
    float4 bias4 = *(const float4*)(bias + n0);
    float bb[4] = {bias4.x, bias4.y, bias4.z, bias4.w};
    #pragma unroll
    for (int i = 0; i < 4; ++i) {
        float4 o;
        o.x = c[i][0] + bb[0]; o.y = c[i][1] + bb[1];
        o.z = c[i][2] + bb[2]; o.w = c[i][3] + bb[3];
        if (relu) {
            o.x = fmaxf(o.x, 0.f); o.y = fmaxf(o.y, 0.f);
            o.z = fmaxf(o.z, 0.f); o.w = fmaxf(o.w, 0.f);
        }
        *(float4*)(C + (size_t)(m0 + i) * N + n0) = o;
    }
}

// ---------------- Flash attention with floor(qk/8) -------------------------
// Q,K,V,O layouts: [b, s, h*64+d]  (i.e. (B*S, 512) with head-major columns).
// Grid: (S/64 q-tiles, B*H).  Block: 256 threads.
__global__ __launch_bounds__(256) void attn_kernel(
    const float* __restrict__ Qg, const float* __restrict__ Kg,
    const float* __restrict__ Vg, float* __restrict__ Og)
{
    __shared__ float Qs[64][65];
    __shared__ float Ks[32][65];
    __shared__ float Vs[32][65];
    __shared__ float Ss[64][33];
    __shared__ float mrow[64], lrow[64], crow[64];

    const int tid = threadIdx.x;
    const int bh = blockIdx.y, b = bh >> 3, h = bh & 7;
    const int q0 = blockIdx.x * 64;
    const size_t baseq = ((size_t)b * 2048 + q0) * 512 + h * 64;
    const size_t basek = ((size_t)b * 2048) * 512 + h * 64;

    // load Q tile (64x64)
    #pragma unroll
    for (int j = 0; j < 4; ++j) {
        int f = tid + j * 256;
        int row = f >> 4, c4 = (f & 15) * 4;
        float4 v4 = *(const float4*)(Qg + baseq + (size_t)row * 512 + c4);
        Qs[row][c4] = v4.x; Qs[row][c4 + 1] = v4.y;
        Qs[row][c4 + 2] = v4.z; Qs[row][c4 + 3] = v4.w;
    }
    if (tid < 64) { mrow[tid] = -INFINITY; lrow[tid] = 0.f; crow[tid] = 0.f; }

    float o[16] = {};
    const int qo = tid & 63, dc = (tid >> 6) * 16;     // O ownership
    const int qy = (tid >> 4) * 4, kx = (tid & 15) * 2; // score tile ownership
    const int qr = tid >> 2, sub = tid & 3;             // row-stats ownership
    __syncthreads();

    for (int kt = 0; kt < 64; ++kt) {
        // load K,V tiles (32x64 each)
        #pragma unroll
        for (int j = 0; j < 2; ++j) {
            int f = tid + j * 256;
            int row = f >> 4, c4 = (f & 15) * 4;
            size_t g = basek + (size_t)(kt * 32 + row) * 512 + c4;
            float4 k4 = *(const float4*)(Kg + g);
            Ks[row][c4] = k4.x; Ks[row][c4 + 1] = k4.y;
            Ks[row][c4 + 2] = k4.z; Ks[row][c4 + 3] = k4.w;
            float4 vv = *(const float4*)(Vg + g);
            Vs[row][c4] = vv.x; Vs[row][c4 + 1] = vv.y;
            Vs[row][c4 + 2] = vv.z; Vs[row][c4 + 3] = vv.w;
        }
        __syncthreads();

        // scores: each thread 4q x 2k dots of length 64
        float sacc[4][2] = {};
        for (int d = 0; d < 64; ++d) {
            float b0 = Ks[kx][d], b1 = Ks[kx + 1][d];
            #pragma unroll
            for (int i = 0; i < 4; ++i) {
                float a = Qs[qy + i][d];
                sacc[i][0] = fmaf(a, b0, sacc[i][0]);
                sacc[i][1] = fmaf(a, b1, sacc[i][1]);
            }
        }
        #pragma unroll
        for (int i = 0; i < 4; ++i) {
            Ss[qy + i][kx]     = floorf(sacc[i][0] * 0.125f);
            Ss[qy + i][kx + 1] = floorf(sacc[i][1] * 0.125f);
        }
        __syncthreads();

        // online softmax stats: 4 threads per row
        {
            float mx = -INFINITY;
            #pragma unroll
            for (int i = 0; i < 8; ++i) mx = fmaxf(mx, Ss[qr][sub * 8 + i]);
            mx = fmaxf(mx, __shfl_xor(mx, 1));
            mx = fmaxf(mx, __shfl_xor(mx, 2));
            float mold = mrow[qr];
            float mnew = fmaxf(mold, mx);
            float ps = 0.f;
            #pragma unroll
            for (int i = 0; i < 8; ++i) {
                float p = expf(Ss[qr][sub * 8 + i] - mnew);
                Ss[qr][sub * 8 + i] = p;
                ps += p;
            }
            ps += __shfl_xor(ps, 1);
            ps += __shfl_xor(ps, 2);
            if (sub == 0) {
                float corr = expf(mold - mnew);   // mold=-inf -> 0
                crow[qr] = corr;
                lrow[qr] = lrow[qr] * corr + ps;
                mrow[qr] = mnew;
            }
        }
        __syncthreads();

        // O update: thread owns (q, 16-wide d chunk)
        {
            float corr = crow[qo];
            #pragma unroll
            for (int j = 0; j < 16; ++j) o[j] *= corr;
            for (int kk2 = 0; kk2 < 32; ++kk2) {
                float p = Ss[qo][kk2];
                #pragma unroll
                for (int j = 0; j < 16; ++j)
                    o[j] = fmaf(p, Vs[kk2][dc + j], o[j]);
            }
        }
        __syncthreads();
    }

    float inv = 1.f / lrow[qo];
    size_t ob = baseq + (size_t)qo * 512 + dc;
    #pragma unroll
    for (int j4 = 0; j4 < 4; ++j4) {
        float4 o4 = { o[j4 * 4] * inv, o[j4 * 4 + 1] * inv,
                      o[j4 * 4 + 2] * inv, o[j4 * 4 + 3] * inv };
        *(float4*)(Og + ob + j4 * 4) = o4;
    }
}

// ---------------- fused residual add + LayerNorm (D=512) -------------------
// One 64-lane wave per row; block = 4 waves = 4 rows.
__global__ __launch_bounds__(256) void add_ln_kernel(
    const float* __restrict__ X, const float* __restrict__ R,
    const float* __restrict__ g, const float* __restrict__ beta,
    float* __restrict__ Out)
{
    const int row = blockIdx.x * 4 + (threadIdx.x >> 6);
    const int lane = threadIdx.x & 63;
    const float* xr = X + (size_t)row * 512;
    const float* rr = R + (size_t)row * 512;
    float v[8];
    float s = 0.f, s2 = 0.f;
    #pragma unroll
    for (int j = 0; j < 2; ++j) {
        float4 a = *(const float4*)(xr + lane * 4 + j * 256);
        float4 bb = *(const float4*)(rr + lane * 4 + j * 256);
        float t0 = a.x + bb.x, t1 = a.y + bb.y;
        float t2 = a.z + bb.z, t3 = a.w + bb.w;
        v[j * 4 + 0] = t0; v[j * 4 + 1] = t1;
        v[j * 4 + 2] = t2; v[j * 4 + 3] = t3;
        s += t0 + t1 + t2 + t3;
        s2 += t0 * t0 + t1 * t1 + t2 * t2 + t3 * t3;
    }
    #pragma unroll
    for (int off = 1; off < 64; off <<= 1) {
        s  += __shfl_xor(s, off);
        s2 += __shfl_xor(s2, off);
    }
    const float mean = s * (1.f / 512.f);
    const float var = s2 * (1.f / 512.f) - mean * mean;
    const float rs = 1.f / sqrtf(var + 1e-5f);
    #pragma unroll
    for (int j = 0; j < 2; ++j) {
        float4 gg = *(const float4*)(g + lane * 4 + j * 256);
        float4 be = *(const float4*)(beta + lane * 4 + j * 256);
        float4 o;
        o.x = (v[j * 4 + 0] - mean) * rs * gg.x + be.x;
        o.y = (v[j * 4 + 1] - mean) * rs * gg.y + be.y;
        o.z = (v[j * 4 + 2] - mean) * rs * gg.z + be.z;
        o.w = (v[j * 4 + 3] - mean) * rs * gg.w + be.w;
        *(float4*)(Out + (size_t)row * 512 + lane * 4 + j * 256) = o;
    }
}

// ---------------------------------------------------------------------------
extern "C" void kernel_launch(void* const* d_in, const int* in_sizes, int n_in,
                              void* d_out, int out_size, void* d_ws, size_t ws_size,
                              hipStream_t stream)
{
    const float* x   = (const float*)d_in[0];
    const float* enc = (const float*)d_in[1];
    // d_in[2], d_in[3]: masks — dead in the reference.
    const float* sa_Wq = (const float*)d_in[4],  *sa_qb = (const float*)d_in[5];
    const float* sa_Wk = (const float*)d_in[6],  *sa_kb = (const float*)d_in[7];
    const float* sa_Wv = (const float*)d_in[8],  *sa_vb = (const float*)d_in[9];
    const float* sa_Wo = (const float*)d_in[10], *sa_ob = (const float*)d_in[11];
    const float* ca_Wq = (const float*)d_in[12], *ca_qb = (const float*)d_in[13];
    const float* ca_Wk = (const float*)d_in[14], *ca_kb = (const float*)d_in[15];
    const float* ca_Wv = (const float*)d_in[16], *ca_vb = (const float*)d_in[17];
    const float* ca_Wo = (const float*)d_in[18], *ca_ob = (const float*)d_in[19];
    const float* ff_W1 = (const float*)d_in[20], *ff_b1 = (const float*)d_in[21];
    const float* ff_W2 = (const float*)d_in[22], *ff_b2 = (const float*)d_in[23];
    const float* ln0_g = (const float*)d_in[24], *ln0_b = (const float*)d_in[25];
    const float* ln1_g = (const float*)d_in[26], *ln1_b = (const float*)d_in[27];
    const float* ln2_g = (const float*)d_in[28], *ln2_b = (const float*)d_in[29];

    float* ws = (float*)d_ws;
    const size_t M2 = 4096 * 512;          // 2,097,152 elems (8 MB)
    float* q     = ws;
    float* k     = ws + 1 * M2;
    float* v     = ws + 2 * M2;
    float* attnb = ws + 3 * M2;
    float* proj  = ws + 4 * M2;            // also ff2 output
    float* x1    = ws + 5 * M2;
    float* x2    = ws + 6 * M2;
    float* ff1   = ws;                     // overlays q..attnb (32 MB), dead by FF phase
    float* out   = (float*)d_out;

    dim3 blk(256);
    dim3 g512(8, 64);     // N=512 gemms: (N/64, M/64)
    dim3 g2048(32, 64);   // N=2048 gemm
    dim3 gattn(32, 16);   // (S/64, B*H)
    dim3 gln(1024);       // 4096 rows / 4

    // ---- self-attention ----
    gemm_bias_kernel<<<g512, blk, 0, stream>>>(x, sa_Wq, sa_qb, q, 4096, 512, 512, 0);
    gemm_bias_kernel<<<g512, blk, 0, stream>>>(x, sa_Wk, sa_kb, k, 4096, 512, 512, 0);
    gemm_bias_kernel<<<g512, blk, 0, stream>>>(x, sa_Wv, sa_vb, v, 4096, 512, 512, 0);
    attn_kernel<<<gattn, blk, 0, stream>>>(q, k, v, attnb);
    gemm_bias_kernel<<<g512, blk, 0, stream>>>(attnb, sa_Wo, sa_ob, proj, 4096, 512, 512, 0);
    add_ln_kernel<<<gln, blk, 0, stream>>>(x, proj, ln0_g, ln0_b, x1);

    // ---- cross-attention ----
    gemm_bias_kernel<<<g512, blk, 0, stream>>>(x1, ca_Wq, ca_qb, q, 4096, 512, 512, 0);
    gemm_bias_kernel<<<g512, blk, 0, stream>>>(enc, ca_Wk, ca_kb, k, 4096, 512, 512, 0);
    gemm_bias_kernel<<<g512, blk, 0, stream>>>(enc, ca_Wv, ca_vb, v, 4096, 512, 512, 0);
    attn_kernel<<<gattn, blk, 0, stream>>>(q, k, v, attnb);
    gemm_bias_kernel<<<g512, blk, 0, stream>>>(attnb, ca_Wo, ca_ob, proj, 4096, 512, 512, 0);
    add_ln_kernel<<<gln, blk, 0, stream>>>(x1, proj, ln1_g, ln1_b, x2);

    // ---- feed-forward ----
    gemm_bias_kernel<<<g2048, blk, 0, stream>>>(x2, ff_W1, ff_b1, ff1, 4096, 2048, 512, 1);
    gemm_bias_kernel<<<g512, blk, 0, stream>>>(ff1, ff_W2, ff_b2, proj, 4096, 512, 2048, 0);
    add_ln_kernel<<<gln, blk, 0, stream>>>(x2, proj, ln2_g, ln2_b, out);
}

// Round 2
// 466.772 us; speedup vs baseline: 3.2273x; 3.2273x over previous
//
#include <hip/hip_runtime.h>
#include <math.h>

// ---------------------------------------------------------------------------
// Decoder block: B=2, S=2048, D=512, H=8, DK=64, FF=2048.
// bf16 MFMA everywhere; QK^T uses bf16x3 split to preserve floor(qk/8).
// ---------------------------------------------------------------------------

typedef __attribute__((ext_vector_type(8))) short short8;  // 8 bf16 (4 VGPRs)
typedef __attribute__((ext_vector_type(4))) float f32x4;

#define MFMA16(a, b, c) __builtin_amdgcn_mfma_f32_16x16x32_bf16((a), (b), (c), 0, 0, 0)

__device__ __forceinline__ unsigned short f2bf(float f) {
    unsigned int u = __float_as_uint(f);
    u += 0x7fffu + ((u >> 16) & 1u);          // RNE
    return (unsigned short)(u >> 16);
}
__device__ __forceinline__ float bf2f(unsigned short h) {
    return __uint_as_float(((unsigned int)h) << 16);
}

// ---------------- bf16 MFMA GEMM: C = A(f32)@W(f32) + bias -----------------
// tile 128x64, BK=64, 4 waves. MODE: 0=f32 out (+RELU), 1=hi/lo bf16 dual out,
// 2=transposed bf16 out Vt[b][h][d][key] (N must be 512 head-major).
template <int MODE, bool RELU>
__global__ __launch_bounds__(256, 4) void gemm_k(
    const float* __restrict__ A, const float* __restrict__ W,
    const float* __restrict__ bias, float* __restrict__ Cf,
    unsigned short* __restrict__ Ohi, unsigned short* __restrict__ Olo,
    int M, int N, int K)
{
    __shared__ __align__(16) unsigned short As[128][72];
    __shared__ __align__(16) unsigned short Bs[64][72];   // transposed: Bs[n][k]
    const int tid = threadIdx.x;
    const int wv = tid >> 6;
    const int lane = tid & 63, l15 = lane & 15, l4 = lane >> 4;
    const int bm = blockIdx.y * 128, bn = blockIdx.x * 64;

    f32x4 acc[2][4];
    #pragma unroll
    for (int i = 0; i < 2; ++i)
        #pragma unroll
        for (int j = 0; j < 4; ++j) acc[i][j] = (f32x4){0.f, 0.f, 0.f, 0.f};

    const int ar = tid >> 3, ac = (tid & 7) * 8;   // A staging: row, 8-elem chunk
    const int bnn = tid & 63, bkc = tid >> 6;      // B staging: col n, k-chunk

    for (int k0 = 0; k0 < K; k0 += 64) {
        __syncthreads();
        // stage A: 128x64 f32 -> bf16, row-major [m][k]
        #pragma unroll
        for (int p = 0; p < 4; ++p) {
            int row = ar + p * 32;
            const float* src = A + (size_t)(bm + row) * K + k0 + ac;
            float4 v0 = *(const float4*)src;
            float4 v1 = *(const float4*)(src + 4);
            short8 w;
            w[0] = f2bf(v0.x); w[1] = f2bf(v0.y); w[2] = f2bf(v0.z); w[3] = f2bf(v0.w);
            w[4] = f2bf(v1.x); w[5] = f2bf(v1.y); w[6] = f2bf(v1.z); w[7] = f2bf(v1.w);
            *(short8*)&As[row][ac] = w;
        }
        // stage B transposed: Bs[n][k]; coalesced column reads of W[K][N]
        #pragma unroll
        for (int p = 0; p < 2; ++p) {
            int kc = bkc + p * 4;    // 0..7
            const float* src = W + (size_t)(k0 + kc * 8) * N + bn + bnn;
            short8 w;
            #pragma unroll
            for (int j = 0; j < 8; ++j) w[j] = f2bf(src[(size_t)j * N]);
            *(short8*)&Bs[bnn][kc * 8] = w;
        }
        __syncthreads();
        #pragma unroll
        for (int kk = 0; kk < 2; ++kk) {
            const int ko = kk * 32 + l4 * 8;
            short8 a0 = *(const short8*)&As[wv * 32 + l15][ko];
            short8 a1 = *(const short8*)&As[wv * 32 + 16 + l15][ko];
            #pragma unroll
            for (int nf = 0; nf < 4; ++nf) {
                short8 bfr = *(const short8*)&Bs[nf * 16 + l15][ko];
                acc[0][nf] = MFMA16(a0, bfr, acc[0][nf]);
                acc[1][nf] = MFMA16(a1, bfr, acc[1][nf]);
            }
        }
    }
    // epilogue: C row = m0 + r, col = n  (col=lane&15, row=(lane>>4)*4+reg)
    #pragma unroll
    for (int nf = 0; nf < 4; ++nf) {
        const int n = bn + nf * 16 + l15;
        const float bv = bias[n];
        #pragma unroll
        for (int mi = 0; mi < 2; ++mi) {
            const int m0 = bm + wv * 32 + mi * 16 + l4 * 4;
            if (MODE == 2) {
                ushort4 pk;
                pk.x = f2bf(acc[mi][nf][0] + bv);
                pk.y = f2bf(acc[mi][nf][1] + bv);
                pk.z = f2bf(acc[mi][nf][2] + bv);
                pk.w = f2bf(acc[mi][nf][3] + bv);
                const int h = n >> 6, d = n & 63, bb = m0 >> 11, key = m0 & 2047;
                *(ushort4*)(Ohi + ((((size_t)bb * 8 + h) * 64 + d) * 2048 + key)) = pk;
            } else {
                #pragma unroll
                for (int r = 0; r < 4; ++r) {
                    float v = acc[mi][nf][r] + bv;
                    if (RELU) v = fmaxf(v, 0.f);
                    size_t idx = (size_t)(m0 + r) * N + n;
                    if (MODE == 0) {
                        Cf[idx] = v;
                    } else {  // MODE 1: hi/lo split
                        unsigned short hi = f2bf(v);
                        Ohi[idx] = hi;
                        Olo[idx] = f2bf(v - bf2f(hi));
                    }
                }
            }
        }
    }
}

// ---------------- MFMA flash attention with floor(qk/8) --------------------
// Qh/Ql/Kh/Kl: [B*S, 512] bf16 head-major cols.  Vt: [b][h][d][2048] bf16.
// Og: [B*S, 512] f32.  Grid (S/64, B*H), block 256 (4 waves x 16 q-rows).
__global__ __launch_bounds__(256, 3) void attn_mfma(
    const unsigned short* __restrict__ Qh, const unsigned short* __restrict__ Ql,
    const unsigned short* __restrict__ Kh, const unsigned short* __restrict__ Kl,
    const unsigned short* __restrict__ Vt, float* __restrict__ Og)
{
    __shared__ __align__(16) unsigned short KH[64][72];
    __shared__ __align__(16) unsigned short KL[64][72];
    __shared__ __align__(16) unsigned short VT[64][72];   // [d][key]
    __shared__ __align__(16) unsigned short QU[2][64][72]; // [0] reused as P

    const int tid = threadIdx.x;
    const int wv = tid >> 6;
    const int lane = tid & 63, l15 = lane & 15, l4 = lane >> 4;
    const int bh = blockIdx.y, b = bh >> 3, h = bh & 7;
    const int q0 = blockIdx.x * 64;
    const int sr = tid >> 3, sc = (tid & 7) * 8;

    // stage Q hi/lo tiles
    #pragma unroll
    for (int p = 0; p < 2; ++p) {
        int r = sr + p * 32;
        size_t g = ((size_t)(b * 2048 + q0 + r)) * 512 + h * 64 + sc;
        *(uint4*)&QU[0][r][sc] = *(const uint4*)(Qh + g);
        *(uint4*)&QU[1][r][sc] = *(const uint4*)(Ql + g);
    }
    __syncthreads();
    // Q fragments to registers (rows wv*16+l15, k = kk*32 + l4*8)
    short8 qh[2], ql[2];
    {
        const int am = wv * 16 + l15;
        qh[0] = *(const short8*)&QU[0][am][l4 * 8];
        qh[1] = *(const short8*)&QU[0][am][32 + l4 * 8];
        ql[0] = *(const short8*)&QU[1][am][l4 * 8];
        ql[1] = *(const short8*)&QU[1][am][32 + l4 * 8];
    }

    f32x4 o[4];
    #pragma unroll
    for (int i = 0; i < 4; ++i) o[i] = (f32x4){0.f, 0.f, 0.f, 0.f};
    float mrow[4] = {-INFINITY, -INFINITY, -INFINITY, -INFINITY};
    float lrow[4] = {0.f, 0.f, 0.f, 0.f};

    for (int kt = 0; kt < 32; ++kt) {
        const int k0 = kt * 64;
        __syncthreads();   // prev iteration's reads done
        #pragma unroll
        for (int p = 0; p < 2; ++p) {
            int r = sr + p * 32;
            size_t gk = ((size_t)(b * 2048 + k0 + r)) * 512 + h * 64 + sc;
            *(uint4*)&KH[r][sc] = *(const uint4*)(Kh + gk);
            *(uint4*)&KL[r][sc] = *(const uint4*)(Kl + gk);
            size_t gv = ((size_t)(bh * 64 + r)) * 2048 + k0 + sc;  // r = d here
            *(uint4*)&VT[r][sc] = *(const uint4*)(Vt + gv);
        }
        __syncthreads();

        // QK^T: wave's 16 rows x 64 keys; bf16x3 for fp32-equivalent floor
        f32x4 s[4];
        #pragma unroll
        for (int f = 0; f < 4; ++f) {
            s[f] = (f32x4){0.f, 0.f, 0.f, 0.f};
            const int krow = f * 16 + l15;
            #pragma unroll
            for (int kk = 0; kk < 2; ++kk) {
                const int ko = kk * 32 + l4 * 8;
                short8 kbh = *(const short8*)&KH[krow][ko];
                short8 kbl = *(const short8*)&KL[krow][ko];
                s[f] = MFMA16(ql[kk], kbh, s[f]);
                s[f] = MFMA16(qh[kk], kbl, s[f]);
                s[f] = MFMA16(qh[kk], kbh, s[f]);
            }
        }

        // online softmax: reg slot r = query row (l4*4+r); cols f*16+l15
        float pv[4][4];
        #pragma unroll
        for (int r = 0; r < 4; ++r) {
            float t0 = floorf(s[0][r] * 0.125f);
            float t1 = floorf(s[1][r] * 0.125f);
            float t2 = floorf(s[2][r] * 0.125f);
            float t3 = floorf(s[3][r] * 0.125f);
            float mx = fmaxf(fmaxf(t0, t1), fmaxf(t2, t3));
            mx = fmaxf(mx, __shfl_xor(mx, 1));
            mx = fmaxf(mx, __shfl_xor(mx, 2));
            mx = fmaxf(mx, __shfl_xor(mx, 4));
            mx = fmaxf(mx, __shfl_xor(mx, 8));
            float mnew = fmaxf(mrow[r], mx);
            float corr = expf(mrow[r] - mnew);     // -inf -> 0 first tile
            float p0 = expf(t0 - mnew), p1 = expf(t1 - mnew);
            float p2 = expf(t2 - mnew), p3 = expf(t3 - mnew);
            float ps = p0 + p1 + p2 + p3;
            ps += __shfl_xor(ps, 1);
            ps += __shfl_xor(ps, 2);
            ps += __shfl_xor(ps, 4);
            ps += __shfl_xor(ps, 8);
            lrow[r] = lrow[r] * corr + ps;
            mrow[r] = mnew;
            pv[0][r] = p0; pv[1][r] = p1; pv[2][r] = p2; pv[3][r] = p3;
            o[0][r] *= corr; o[1][r] *= corr; o[2][r] *= corr; o[3][r] *= corr;
        }

        // P -> LDS (each wave writes/reads only its own 16 rows; no barrier)
        #pragma unroll
        for (int f = 0; f < 4; ++f)
            #pragma unroll
            for (int r = 0; r < 4; ++r)
                QU[0][wv * 16 + l4 * 4 + r][f * 16 + l15] = f2bf(pv[f][r]);

        short8 pa[2];
        {
            const int am = wv * 16 + l15;
            pa[0] = *(const short8*)&QU[0][am][l4 * 8];
            pa[1] = *(const short8*)&QU[0][am][32 + l4 * 8];
        }
        #pragma unroll
        for (int df = 0; df < 4; ++df) {
            const int dn = df * 16 + l15;
            #pragma unroll
            for (int kk = 0; kk < 2; ++kk) {
                short8 vb = *(const short8*)&VT[dn][kk * 32 + l4 * 8];
                o[df] = MFMA16(pa[kk], vb, o[df]);
            }
        }
    }

    // epilogue: O / l  -> f32 out [token][512]
    #pragma unroll
    for (int df = 0; df < 4; ++df) {
        const int col = h * 64 + df * 16 + l15;
        #pragma unroll
        for (int r = 0; r < 4; ++r) {
            const int row = b * 2048 + q0 + wv * 16 + l4 * 4 + r;
            Og[(size_t)row * 512 + col] = o[df][r] / lrow[r];
        }
    }
}

// ---------------- fused residual add + LayerNorm (D=512) -------------------
__global__ __launch_bounds__(256) void add_ln_kernel(
    const float* __restrict__ X, const float* __restrict__ R,
    const float* __restrict__ g, const float* __restrict__ beta,
    float* __restrict__ Out)
{
    const int row = blockIdx.x * 4 + (threadIdx.x >> 6);
    const int lane = threadIdx.x & 63;
    const float* xr = X + (size_t)row * 512;
    const float* rr = R + (size_t)row * 512;
    float v[8];
    float s = 0.f, s2 = 0.f;
    #pragma unroll
    for (int j = 0; j < 2; ++j) {
        float4 a = *(const float4*)(xr + lane * 4 + j * 256);
        float4 bb = *(const float4*)(rr + lane * 4 + j * 256);
        float t0 = a.x + bb.x, t1 = a.y + bb.y;
        float t2 = a.z + bb.z, t3 = a.w + bb.w;
        v[j * 4 + 0] = t0; v[j * 4 + 1] = t1;
        v[j * 4 + 2] = t2; v[j * 4 + 3] = t3;
        s += t0 + t1 + t2 + t3;
        s2 += t0 * t0 + t1 * t1 + t2 * t2 + t3 * t3;
    }
    #pragma unroll
    for (int off = 1; off < 64; off <<= 1) {
        s  += __shfl_xor(s, off);
        s2 += __shfl_xor(s2, off);
    }
    const float mean = s * (1.f / 512.f);
    const float var = s2 * (1.f / 512.f) - mean * mean;
    const float rs = 1.f / sqrtf(var + 1e-5f);
    #pragma unroll
    for (int j = 0; j < 2; ++j) {
        float4 gg = *(const float4*)(g + lane * 4 + j * 256);
        float4 be = *(const float4*)(beta + lane * 4 + j * 256);
        float4 o;
        o.x = (v[j * 4 + 0] - mean) * rs * gg.x + be.x;
        o.y = (v[j * 4 + 1] - mean) * rs * gg.y + be.y;
        o.z = (v[j * 4 + 2] - mean) * rs * gg.z + be.z;
        o.w = (v[j * 4 + 3] - mean) * rs * gg.w + be.w;
        *(float4*)(Out + (size_t)row * 512 + lane * 4 + j * 256) = o;
    }
}

// ---------------------------------------------------------------------------
extern "C" void kernel_launch(void* const* d_in, const int* in_sizes, int n_in,
                              void* d_out, int out_size, void* d_ws, size_t ws_size,
                              hipStream_t stream)
{
    const float* x   = (const float*)d_in[0];
    const float* enc = (const float*)d_in[1];
    // d_in[2], d_in[3]: masks — dead in the reference.
    const float* sa_Wq = (const float*)d_in[4],  *sa_qb = (const float*)d_in[5];
    const float* sa_Wk = (const float*)d_in[6],  *sa_kb = (const float*)d_in[7];
    const float* sa_Wv = (const float*)d_in[8],  *sa_vb = (const float*)d_in[9];
    const float* sa_Wo = (const float*)d_in[10], *sa_ob = (const float*)d_in[11];
    const float* ca_Wq = (const float*)d_in[12], *ca_qb = (const float*)d_in[13];
    const float* ca_Wk = (const float*)d_in[14], *ca_kb = (const float*)d_in[15];
    const float* ca_Wv = (const float*)d_in[16], *ca_vb = (const float*)d_in[17];
    const float* ca_Wo = (const float*)d_in[18], *ca_ob = (const float*)d_in[19];
    const float* ff_W1 = (const float*)d_in[20], *ff_b1 = (const float*)d_in[21];
    const float* ff_W2 = (const float*)d_in[22], *ff_b2 = (const float*)d_in[23];
    const float* ln0_g = (const float*)d_in[24], *ln0_b = (const float*)d_in[25];
    const float* ln1_g = (const float*)d_in[26], *ln1_b = (const float*)d_in[27];
    const float* ln2_g = (const float*)d_in[28], *ln2_b = (const float*)d_in[29];

    char* base = (char*)d_ws;
    const size_t MB = 1u << 20;
    unsigned short* qhi = (unsigned short*)(base + 0 * MB);     // 4MB
    unsigned short* qlo = (unsigned short*)(base + 4 * MB);
    unsigned short* khi = (unsigned short*)(base + 8 * MB);
    unsigned short* klo = (unsigned short*)(base + 12 * MB);
    unsigned short* vt  = (unsigned short*)(base + 16 * MB);
    float* attnb = (float*)(base + 20 * MB);                    // 8MB
    float* x1    = (float*)(base + 28 * MB);                    // 8MB
    float* x2    = (float*)(base + 36 * MB);                    // 8MB
    float* proj  = (float*)(base + 44 * MB);                    // 8MB
    float* ff1   = (float*)(base + 0 * MB);  // 32MB, overlays q/k/v/attnb/x1-head (all dead)
    float* out   = (float*)d_out;

    dim3 blk(256);
    dim3 g512(8, 32);    // N=512 gemms: (N/64, M/128)
    dim3 g2048(32, 32);  // N=2048 gemm
    dim3 gattn(32, 16);  // (S/64, B*H)
    dim3 gln(1024);      // 4096 rows / 4

    // ---- self-attention ----
    gemm_k<1, false><<<g512, blk, 0, stream>>>(x, sa_Wq, sa_qb, nullptr, qhi, qlo, 4096, 512, 512);
    gemm_k<1, false><<<g512, blk, 0, stream>>>(x, sa_Wk, sa_kb, nullptr, khi, klo, 4096, 512, 512);
    gemm_k<2, false><<<g512, blk, 0, stream>>>(x, sa_Wv, sa_vb, nullptr, vt, nullptr, 4096, 512, 512);
    attn_mfma<<<gattn, blk, 0, stream>>>(qhi, qlo, khi, klo, vt, attnb);
    gemm_k<0, false><<<g512, blk, 0, stream>>>(attnb, sa_Wo, sa_ob, proj, nullptr, nullptr, 4096, 512, 512);
    add_ln_kernel<<<gln, blk, 0, stream>>>(x, proj, ln0_g, ln0_b, x1);

    // ---- cross-attention ----
    gemm_k<1, false><<<g512, blk, 0, stream>>>(x1, ca_Wq, ca_qb, nullptr, qhi, qlo, 4096, 512, 512);
    gemm_k<1, false><<<g512, blk, 0, stream>>>(enc, ca_Wk, ca_kb, nullptr, khi, klo, 4096, 512, 512);
    gemm_k<2, false><<<g512, blk, 0, stream>>>(enc, ca_Wv, ca_vb, nullptr, vt, nullptr, 4096, 512, 512);
    attn_mfma<<<gattn, blk, 0, stream>>>(qhi, qlo, khi, klo, vt, attnb);
    gemm_k<0, false><<<g512, blk, 0, stream>>>(attnb, ca_Wo, ca_ob, proj, nullptr, nullptr, 4096, 512, 512);
    add_ln_kernel<<<gln, blk, 0, stream>>>(x1, proj, ln1_g, ln1_b, x2);

    // ---- feed-forward ----
    gemm_k<0, true><<<g2048, blk, 0, stream>>>(x2, ff_W1, ff_b1, ff1, nullptr, nullptr, 4096, 2048, 512);
    gemm_k<0, false><<<g512, blk, 0, stream>>>(ff1, ff_W2, ff_b2, proj, nullptr, nullptr, 4096, 512, 2048);
    add_ln_kernel<<<gln, blk, 0, stream>>>(x2, proj, ln2_g, ln2_b, out);
}

// Round 3
// 297.993 us; speedup vs baseline: 5.0553x; 1.5664x over previous
//
#include <hip/hip_runtime.h>
#include <math.h>

// ---------------------------------------------------------------------------
// Decoder block: B=2, S=2048, D=512, H=8, DK=64, FF=2048.
// All matmuls bf16 MFMA (16x16x32). QK^T uses bf16x3 split so floor(qk/8)
// matches fp32. Weights pre-transposed+converted to bf16 [N][K].
// LDS everywhere: [rows][64] bf16 (128B rows) with XOR-16B swizzle
// (phys_short = col ^ ((row&7)*8)); staged via global_load_lds with
// inverse-swizzled global source (linear LDS dest).
// ---------------------------------------------------------------------------

typedef __attribute__((ext_vector_type(8))) short short8;   // 8 bf16
typedef __attribute__((ext_vector_type(4))) float f32x4;

#define MFMA16(a, b, c) __builtin_amdgcn_mfma_f32_16x16x32_bf16((a), (b), (c), 0, 0, 0)

__device__ __forceinline__ unsigned short f2bf(float f) {
    unsigned int u = __float_as_uint(f);
    u += 0x7fffu + ((u >> 16) & 1u);          // RNE
    return (unsigned short)(u >> 16);
}
__device__ __forceinline__ float bf2f(unsigned short h) {
    return __uint_as_float(((unsigned int)h) << 16);
}
__device__ __forceinline__ void g2l16(const void* g, void* l) {
    __builtin_amdgcn_global_load_lds(
        (const __attribute__((address_space(1))) unsigned int*)g,
        (__attribute__((address_space(3))) unsigned int*)l, 16, 0, 0);
}
// swizzled short-index within a [rows][64]-short LDS tile
__device__ __forceinline__ int swz(int row, int col) {
    return row * 64 + (col ^ ((row & 7) * 8));
}

// ---------------- bf16 GEMM: C[M,N] = A[M,K] @ Bt[N,K]^T + bias ------------
// BM=128, BK=64, 4 waves. MODE: 0 = f32 out; 1 = hi/lo bf16 dual out;
// 2 = transposed bf16 out Vt[b][h][d][key]; 3 = bf16 out + ReLU.
template <int BN, int MODE>
__global__ __launch_bounds__(256, BN == 128 ? 3 : 4) void gemm_bf16(
    const unsigned short* __restrict__ A, const unsigned short* __restrict__ Bt,
    const float* __restrict__ bias, float* __restrict__ Cf,
    unsigned short* __restrict__ O1, unsigned short* __restrict__ O2,
    int M, int N, int K)
{
    __shared__ unsigned short As[128 * 64];
    __shared__ unsigned short Bs[BN * 64];
    const int tid = threadIdx.x, wv = tid >> 6, lane = tid & 63;
    const int l15 = lane & 15, l4 = lane >> 4;
    const int bm = blockIdx.y * 128, bn = blockIdx.x * BN;
    constexpr int MI = (BN == 128) ? 4 : 2;
    const int wrow = (BN == 128) ? ((wv >> 1) * 64) : (wv * 32);
    const int wcol = (BN == 128) ? ((wv & 1) * 64) : 0;

    f32x4 acc[MI][4];
    #pragma unroll
    for (int i = 0; i < MI; ++i)
        #pragma unroll
        for (int j = 0; j < 4; ++j) acc[i][j] = (f32x4){0.f, 0.f, 0.f, 0.f};

    const int srow = lane >> 3;                       // 0..7 within 8-row chunk
    const int sch  = (lane & 7) ^ srow;               // inverse-swizzled 16B chunk
    const unsigned short* Asrc = A + (size_t)(bm + wv * 32 + srow) * K + sch * 8;
    const unsigned short* Bsrc = Bt + (size_t)(bn + ((BN == 128) ? wv * 32 : wv * 16) + srow) * K + sch * 8;

    for (int k0 = 0; k0 < K; k0 += 64) {
        __syncthreads();
        #pragma unroll
        for (int j = 0; j < 4; ++j)
            g2l16(Asrc + (size_t)j * 8 * K + k0, &As[(wv * 32 + j * 8) * 64]);
        if (BN == 128) {
            #pragma unroll
            for (int j = 0; j < 4; ++j)
                g2l16(Bsrc + (size_t)j * 8 * K + k0, &Bs[(wv * 32 + j * 8) * 64]);
        } else {
            #pragma unroll
            for (int j = 0; j < 2; ++j)
                g2l16(Bsrc + (size_t)j * 8 * K + k0, &Bs[(wv * 16 + j * 8) * 64]);
        }
        __syncthreads();
        #pragma unroll
        for (int kk = 0; kk < 2; ++kk) {
            const int kc = kk * 32 + l4 * 8;
            short8 af[MI], bfr[4];
            #pragma unroll
            for (int mi = 0; mi < MI; ++mi)
                af[mi] = *(const short8*)&As[swz(wrow + mi * 16 + l15, kc)];
            #pragma unroll
            for (int nf = 0; nf < 4; ++nf)
                bfr[nf] = *(const short8*)&Bs[swz(wcol + nf * 16 + l15, kc)];
            #pragma unroll
            for (int mi = 0; mi < MI; ++mi)
                #pragma unroll
                for (int nf = 0; nf < 4; ++nf)
                    acc[mi][nf] = MFMA16(af[mi], bfr[nf], acc[mi][nf]);
        }
    }

    // epilogue: C col = l15-block, row = l4*4 + reg
    #pragma unroll
    for (int nf = 0; nf < 4; ++nf) {
        const int n = bn + wcol + nf * 16 + l15;
        const float bv = bias[n];
        #pragma unroll
        for (int mi = 0; mi < MI; ++mi) {
            const int m0 = bm + wrow + mi * 16 + l4 * 4;
            if (MODE == 2) {
                ushort4 pk;
                pk.x = f2bf(acc[mi][nf][0] + bv);
                pk.y = f2bf(acc[mi][nf][1] + bv);
                pk.z = f2bf(acc[mi][nf][2] + bv);
                pk.w = f2bf(acc[mi][nf][3] + bv);
                const int hh = n >> 6, dd = n & 63, bb = m0 >> 11, key = m0 & 2047;
                *(ushort4*)(O1 + ((((size_t)bb * 8 + hh) * 64 + dd) * 2048 + key)) = pk;
            } else {
                #pragma unroll
                for (int r = 0; r < 4; ++r) {
                    float v = acc[mi][nf][r] + bv;
                    size_t idx = (size_t)(m0 + r) * N + n;
                    if (MODE == 0) {
                        Cf[idx] = v;
                    } else if (MODE == 1) {
                        unsigned short hi = f2bf(v);
                        O1[idx] = hi;
                        O2[idx] = f2bf(v - bf2f(hi));
                    } else {  // MODE 3
                        O1[idx] = f2bf(fmaxf(v, 0.f));
                    }
                }
            }
        }
    }
}

// ---------------- MFMA flash attention with floor(qk/8) --------------------
// Qh/Ql/Kh/Kl: [B*S, 512] bf16 head-major cols. Vt: [b][h][d][2048] bf16.
// Ob: [B*S, 512] bf16. Grid (S/64, B*H), block 256 (4 waves x 16 q-rows).
__global__ __launch_bounds__(256, 2) void attn_mfma(
    const unsigned short* __restrict__ Qh, const unsigned short* __restrict__ Ql,
    const unsigned short* __restrict__ Kh, const unsigned short* __restrict__ Kl,
    const unsigned short* __restrict__ Vt, unsigned short* __restrict__ Ob)
{
    __shared__ unsigned short QH[64 * 64];   // reused as P after q-frag load
    __shared__ unsigned short QL[64 * 64];
    __shared__ unsigned short KH[64 * 64];
    __shared__ unsigned short KL[64 * 64];
    __shared__ unsigned short VT[64 * 64];   // [d][key]

    const int tid = threadIdx.x, wv = tid >> 6, lane = tid & 63;
    const int l15 = lane & 15, l4 = lane >> 4;
    const int bh = blockIdx.y, b = bh >> 3, h = bh & 7;
    const int q0 = blockIdx.x * 64;
    const int srow = lane >> 3;
    const int sch  = (lane & 7) ^ srow;

    // stage Q hi/lo (each wave stages exactly its own 16 rows)
    {
        const unsigned short* qh_src = Qh + (size_t)(b * 2048 + q0 + wv * 16 + srow) * 512 + h * 64 + sch * 8;
        const unsigned short* ql_src = Ql + (size_t)(b * 2048 + q0 + wv * 16 + srow) * 512 + h * 64 + sch * 8;
        #pragma unroll
        for (int j = 0; j < 2; ++j) {
            g2l16(qh_src + (size_t)j * 8 * 512, &QH[(wv * 16 + j * 8) * 64]);
            g2l16(ql_src + (size_t)j * 8 * 512, &QL[(wv * 16 + j * 8) * 64]);
        }
    }
    __syncthreads();
    short8 qh[2], ql[2];
    #pragma unroll
    for (int kk = 0; kk < 2; ++kk) {
        qh[kk] = *(const short8*)&QH[swz(wv * 16 + l15, kk * 32 + l4 * 8)];
        ql[kk] = *(const short8*)&QL[swz(wv * 16 + l15, kk * 32 + l4 * 8)];
    }

    const unsigned short* kh_src = Kh + (size_t)(b * 2048 + wv * 16 + srow) * 512 + h * 64 + sch * 8;
    const unsigned short* kl_src = Kl + (size_t)(b * 2048 + wv * 16 + srow) * 512 + h * 64 + sch * 8;
    const unsigned short* vt_src = Vt + (size_t)(bh * 64 + wv * 16 + srow) * 2048 + sch * 8;

    f32x4 o[4], lacc;
    #pragma unroll
    for (int i = 0; i < 4; ++i) o[i] = (f32x4){0.f, 0.f, 0.f, 0.f};
    lacc = (f32x4){0.f, 0.f, 0.f, 0.f};
    float m[4] = {-INFINITY, -INFINITY, -INFINITY, -INFINITY};

    const short one_s = (short)(l15 == 0 ? 0x3F80 : 0);     // bf16 1.0 in col 0
    const short8 oneb = {one_s, one_s, one_s, one_s, one_s, one_s, one_s, one_s};

    for (int kt = 0; kt < 32; ++kt) {
        const size_t k0 = kt * 64;
        __syncthreads();
        #pragma unroll
        for (int j = 0; j < 2; ++j) {
            g2l16(kh_src + (k0 + j * 8) * 512, &KH[(wv * 16 + j * 8) * 64]);
            g2l16(kl_src + (k0 + j * 8) * 512, &KL[(wv * 16 + j * 8) * 64]);
            g2l16(vt_src + k0 + (size_t)j * 8 * 2048, &VT[(wv * 16 + j * 8) * 64]);
        }
        __syncthreads();

        // QK^T (bf16x3): wave's 16 q-rows x 64 keys
        f32x4 s[4];
        __builtin_amdgcn_s_setprio(1);
        #pragma unroll
        for (int f = 0; f < 4; ++f) {
            s[f] = (f32x4){0.f, 0.f, 0.f, 0.f};
            #pragma unroll
            for (int kk = 0; kk < 2; ++kk) {
                const int kc = kk * 32 + l4 * 8;
                short8 kbh = *(const short8*)&KH[swz(f * 16 + l15, kc)];
                short8 kbl = *(const short8*)&KL[swz(f * 16 + l15, kc)];
                s[f] = MFMA16(ql[kk], kbh, s[f]);
                s[f] = MFMA16(qh[kk], kbl, s[f]);
                s[f] = MFMA16(qh[kk], kbh, s[f]);
            }
        }
        __builtin_amdgcn_s_setprio(0);

        // floor + row max (16-lane reduce); defer-max (THR=8, scores integer)
        float t[4][4], pmax[4];
        bool need = false;
        #pragma unroll
        for (int r = 0; r < 4; ++r) {
            t[0][r] = floorf(s[0][r] * 0.125f);
            t[1][r] = floorf(s[1][r] * 0.125f);
            t[2][r] = floorf(s[2][r] * 0.125f);
            t[3][r] = floorf(s[3][r] * 0.125f);
            float mx = fmaxf(fmaxf(t[0][r], t[1][r]), fmaxf(t[2][r], t[3][r]));
            mx = fmaxf(mx, __shfl_xor(mx, 1));
            mx = fmaxf(mx, __shfl_xor(mx, 2));
            mx = fmaxf(mx, __shfl_xor(mx, 4));
            mx = fmaxf(mx, __shfl_xor(mx, 8));
            pmax[r] = mx;
            need = need || (mx > m[r] + 8.f);
        }
        if (__any(need)) {
            #pragma unroll
            for (int r = 0; r < 4; ++r) {
                float mnew = fmaxf(m[r], pmax[r]);
                float corr = __expf(m[r] - mnew);    // -inf -> 0 first tile
                o[0][r] *= corr; o[1][r] *= corr; o[2][r] *= corr; o[3][r] *= corr;
                lacc[r] *= corr;
                m[r] = mnew;
            }
        }
        // P = exp(t - m)  (bounded by e^8), bf16 into QH (wave-private rows)
        #pragma unroll
        for (int f = 0; f < 4; ++f)
            #pragma unroll
            for (int r = 0; r < 4; ++r)
                QH[swz(wv * 16 + l4 * 4 + r, f * 16 + l15)] = f2bf(__expf(t[f][r] - m[r]));

        short8 pa[2];
        pa[0] = *(const short8*)&QH[swz(wv * 16 + l15, l4 * 8)];
        pa[1] = *(const short8*)&QH[swz(wv * 16 + l15, 32 + l4 * 8)];

        __builtin_amdgcn_s_setprio(1);
        lacc = MFMA16(pa[0], oneb, lacc);     // row-sum via ones column
        lacc = MFMA16(pa[1], oneb, lacc);
        #pragma unroll
        for (int df = 0; df < 4; ++df) {
            #pragma unroll
            for (int kk = 0; kk < 2; ++kk) {
                short8 vb = *(const short8*)&VT[swz(df * 16 + l15, kk * 32 + l4 * 8)];
                o[df] = MFMA16(pa[kk], vb, o[df]);
            }
        }
        __builtin_amdgcn_s_setprio(0);
    }

    // epilogue: l lives in lanes l15==0 (col 0 of lacc); broadcast + store bf16
    float linv[4];
    #pragma unroll
    for (int r = 0; r < 4; ++r) linv[r] = 1.f / __shfl(lacc[r], lane & 48);
    #pragma unroll
    for (int df = 0; df < 4; ++df)
        #pragma unroll
        for (int r = 0; r < 4; ++r) {
            size_t idx = (size_t)(b * 2048 + q0 + wv * 16 + l4 * 4 + r) * 512 + h * 64 + df * 16 + l15;
            Ob[idx] = f2bf(o[df][r] * linv[r]);
        }
}

// ---------------- fused residual add + LayerNorm (D=512) -------------------
// X: residual branch (bf16 if XBF else f32); R: f32. One wave per row.
template <bool XBF, bool OUTF, bool OUTB>
__global__ __launch_bounds__(256) void add_ln(
    const void* __restrict__ Xv, const float* __restrict__ R,
    const float* __restrict__ g, const float* __restrict__ beta,
    float* __restrict__ OutF, unsigned short* __restrict__ OutB)
{
    const int row = blockIdx.x * 4 + (threadIdx.x >> 6);
    const int lane = threadIdx.x & 63;
    const int c0 = lane * 8;
    float v[8];
    const float* rr = R + (size_t)row * 512 + c0;
    float4 r0 = *(const float4*)rr, r1 = *(const float4*)(rr + 4);
    float xx[8];
    if (XBF) {
        const unsigned short* xr = (const unsigned short*)Xv + (size_t)row * 512 + c0;
        uint4 u = *(const uint4*)xr;
        xx[0] = bf2f(u.x & 0xffff); xx[1] = bf2f(u.x >> 16);
        xx[2] = bf2f(u.y & 0xffff); xx[3] = bf2f(u.y >> 16);
        xx[4] = bf2f(u.z & 0xffff); xx[5] = bf2f(u.z >> 16);
        xx[6] = bf2f(u.w & 0xffff); xx[7] = bf2f(u.w >> 16);
    } else {
        const float* xr = (const float*)Xv + (size_t)row * 512 + c0;
        float4 a0 = *(const float4*)xr, a1 = *(const float4*)(xr + 4);
        xx[0] = a0.x; xx[1] = a0.y; xx[2] = a0.z; xx[3] = a0.w;
        xx[4] = a1.x; xx[5] = a1.y; xx[6] = a1.z; xx[7] = a1.w;
    }
    v[0] = xx[0] + r0.x; v[1] = xx[1] + r0.y; v[2] = xx[2] + r0.z; v[3] = xx[3] + r0.w;
    v[4] = xx[4] + r1.x; v[5] = xx[5] + r1.y; v[6] = xx[6] + r1.z; v[7] = xx[7] + r1.w;
    float s = 0.f, s2 = 0.f;
    #pragma unroll
    for (int j = 0; j < 8; ++j) { s += v[j]; s2 += v[j] * v[j]; }
    #pragma unroll
    for (int off = 1; off < 64; off <<= 1) {
        s  += __shfl_xor(s, off);
        s2 += __shfl_xor(s2, off);
    }
    const float mean = s * (1.f / 512.f);
    const float var = s2 * (1.f / 512.f) - mean * mean;
    const float rs = 1.f / sqrtf(var + 1e-5f);
    float ovals[8];
    const float* gg = g + c0; const float* bb = beta + c0;
    #pragma unroll
    for (int j = 0; j < 8; ++j) ovals[j] = (v[j] - mean) * rs * gg[j] + bb[j];
    if (OUTF) {
        float* po = OutF + (size_t)row * 512 + c0;
        *(float4*)po = (float4){ovals[0], ovals[1], ovals[2], ovals[3]};
        *(float4*)(po + 4) = (float4){ovals[4], ovals[5], ovals[6], ovals[7]};
    }
    if (OUTB) {
        uint4 u;
        u.x = (unsigned)f2bf(ovals[0]) | ((unsigned)f2bf(ovals[1]) << 16);
        u.y = (unsigned)f2bf(ovals[2]) | ((unsigned)f2bf(ovals[3]) << 16);
        u.z = (unsigned)f2bf(ovals[4]) | ((unsigned)f2bf(ovals[5]) << 16);
        u.w = (unsigned)f2bf(ovals[6]) | ((unsigned)f2bf(ovals[7]) << 16);
        *(uint4*)(OutB + (size_t)row * 512 + c0) = u;
    }
}

// ---------------- f32 -> bf16 convert for x and enc ------------------------
__global__ __launch_bounds__(256) void conv_bf16(
    const float* __restrict__ X, const float* __restrict__ E,
    unsigned short* __restrict__ Xb, unsigned short* __restrict__ Eb)
{
    size_t i = ((size_t)blockIdx.x * 256 + threadIdx.x) * 8;
    const float* src; unsigned short* dst; size_t off;
    if (i < 2097152) { src = X; dst = Xb; off = i; }
    else             { src = E; dst = Eb; off = i - 2097152; }
    float4 a = *(const float4*)(src + off), c = *(const float4*)(src + off + 4);
    uint4 u;
    u.x = (unsigned)f2bf(a.x) | ((unsigned)f2bf(a.y) << 16);
    u.y = (unsigned)f2bf(a.z) | ((unsigned)f2bf(a.w) << 16);
    u.z = (unsigned)f2bf(c.x) | ((unsigned)f2bf(c.y) << 16);
    u.w = (unsigned)f2bf(c.z) | ((unsigned)f2bf(c.w) << 16);
    *(uint4*)(dst + off) = u;
}

// ---------------- batched weight transpose+convert: [K][N] f32 -> [N][K] bf16
struct WTJobs {
    const float* src[10];
    unsigned short* dst[10];
    int K[10], N[10];
    int cum[11];
};
__global__ __launch_bounds__(256) void wtrans(WTJobs jb)
{
    int bid = blockIdx.x;
    int z = 0;
    while (bid >= jb.cum[z + 1]) ++z;
    const int lt = bid - jb.cum[z];
    const int K = jb.K[z], N = jb.N[z];
    const int ntx = N >> 5;
    const int tx = lt % ntx, ty = lt / ntx;
    __shared__ float T[32][33];
    const int r = threadIdx.x >> 3, c4 = (threadIdx.x & 7) * 4;
    float4 a = *(const float4*)(jb.src[z] + (size_t)(ty * 32 + r) * N + tx * 32 + c4);
    T[r][c4] = a.x; T[r][c4 + 1] = a.y; T[r][c4 + 2] = a.z; T[r][c4 + 3] = a.w;
    __syncthreads();
    ushort4 o;
    o.x = f2bf(T[c4][r]); o.y = f2bf(T[c4 + 1][r]);
    o.z = f2bf(T[c4 + 2][r]); o.w = f2bf(T[c4 + 3][r]);
    *(ushort4*)(jb.dst[z] + (size_t)(tx * 32 + r) * K + ty * 32 + c4) = o;
}

// ---------------------------------------------------------------------------
extern "C" void kernel_launch(void* const* d_in, const int* in_sizes, int n_in,
                              void* d_out, int out_size, void* d_ws, size_t ws_size,
                              hipStream_t stream)
{
    const float* x   = (const float*)d_in[0];
    const float* enc = (const float*)d_in[1];
    // d_in[2], d_in[3]: masks — dead in the reference.
    const float* Wp[8] = {(const float*)d_in[4],  (const float*)d_in[6],
                          (const float*)d_in[8],  (const float*)d_in[10],
                          (const float*)d_in[12], (const float*)d_in[14],
                          (const float*)d_in[16], (const float*)d_in[18]};
    const float* sa_qb = (const float*)d_in[5],  *sa_kb = (const float*)d_in[7];
    const float* sa_vb = (const float*)d_in[9],  *sa_ob = (const float*)d_in[11];
    const float* ca_qb = (const float*)d_in[13], *ca_kb = (const float*)d_in[15];
    const float* ca_vb = (const float*)d_in[17], *ca_ob = (const float*)d_in[19];
    const float* ff_W1 = (const float*)d_in[20], *ff_b1 = (const float*)d_in[21];
    const float* ff_W2 = (const float*)d_in[22], *ff_b2 = (const float*)d_in[23];
    const float* ln0_g = (const float*)d_in[24], *ln0_b = (const float*)d_in[25];
    const float* ln1_g = (const float*)d_in[26], *ln1_b = (const float*)d_in[27];
    const float* ln2_g = (const float*)d_in[28], *ln2_b = (const float*)d_in[29];

    char* base = (char*)d_ws;
    const size_t MB = 1u << 20;
    unsigned short* wt   = (unsigned short*)(base + 0 * MB);   // 8 MB: 10 transposed bf16 weights
    unsigned short* xb   = (unsigned short*)(base + 8 * MB);   // 4 MB (later reused as x2b)
    unsigned short* encb = (unsigned short*)(base + 12 * MB);  // 4 MB
    unsigned short* x1b  = (unsigned short*)(base + 16 * MB);  // 4 MB
    unsigned short* attnb= (unsigned short*)(base + 20 * MB);  // 4 MB
    unsigned short* vt   = (unsigned short*)(base + 24 * MB);  // 4 MB
    unsigned short* qhi  = (unsigned short*)(base + 28 * MB);  // 4 MB each
    unsigned short* qlo  = (unsigned short*)(base + 32 * MB);
    unsigned short* khi  = (unsigned short*)(base + 36 * MB);
    unsigned short* klo  = (unsigned short*)(base + 40 * MB);
    unsigned short* ffb  = qhi;                                // 16 MB overlay (dead by FF)
    unsigned short* x2b  = xb;                                 // overlay (xb dead after SA QKV)
    float* proj = (float*)(base + 44 * MB);                    // 8 MB
    float* out  = (float*)d_out;

    // transposed weight pointers (shorts)
    unsigned short* wtp[10];
    for (int i = 0; i < 8; ++i) wtp[i] = wt + (size_t)i * 262144;
    wtp[8] = wt + 8u * 262144;            // ff_W1t: [2048][512]
    wtp[9] = wt + 8u * 262144 + 1048576;  // ff_W2t: [512][2048]

    WTJobs jb;
    for (int i = 0; i < 8; ++i) { jb.src[i] = Wp[i]; jb.dst[i] = wtp[i]; jb.K[i] = 512; jb.N[i] = 512; }
    jb.src[8] = ff_W1; jb.dst[8] = wtp[8]; jb.K[8] = 512;  jb.N[8] = 2048;
    jb.src[9] = ff_W2; jb.dst[9] = wtp[9]; jb.K[9] = 2048; jb.N[9] = 512;
    jb.cum[0] = 0;
    for (int i = 0; i < 10; ++i)
        jb.cum[i + 1] = jb.cum[i] + (jb.N[i] >> 5) * (jb.K[i] >> 5);

    dim3 blk(256);
    dim3 g512(8, 32);     // N=512 GEMMs (BN=64)
    dim3 gff1(16, 32);    // N=2048 (BN=128)
    dim3 gattn(32, 16);
    dim3 gln(1024);

    conv_bf16<<<2048, blk, 0, stream>>>(x, enc, xb, encb);
    wtrans<<<jb.cum[10], blk, 0, stream>>>(jb);

    // ---- self-attention ----
    gemm_bf16<64, 1><<<g512, blk, 0, stream>>>(xb, wtp[0], sa_qb, nullptr, qhi, qlo, 4096, 512, 512);
    gemm_bf16<64, 1><<<g512, blk, 0, stream>>>(xb, wtp[1], sa_kb, nullptr, khi, klo, 4096, 512, 512);
    gemm_bf16<64, 2><<<g512, blk, 0, stream>>>(xb, wtp[2], sa_vb, nullptr, vt, nullptr, 4096, 512, 512);
    attn_mfma<<<gattn, blk, 0, stream>>>(qhi, qlo, khi, klo, vt, attnb);
    gemm_bf16<64, 0><<<g512, blk, 0, stream>>>(attnb, wtp[3], sa_ob, proj, nullptr, nullptr, 4096, 512, 512);
    add_ln<false, false, true><<<gln, blk, 0, stream>>>(x, proj, ln0_g, ln0_b, nullptr, x1b);

    // ---- cross-attention ----
    gemm_bf16<64, 1><<<g512, blk, 0, stream>>>(x1b, wtp[4], ca_qb, nullptr, qhi, qlo, 4096, 512, 512);
    gemm_bf16<64, 1><<<g512, blk, 0, stream>>>(encb, wtp[5], ca_kb, nullptr, khi, klo, 4096, 512, 512);
    gemm_bf16<64, 2><<<g512, blk, 0, stream>>>(encb, wtp[6], ca_vb, nullptr, vt, nullptr, 4096, 512, 512);
    attn_mfma<<<gattn, blk, 0, stream>>>(qhi, qlo, khi, klo, vt, attnb);
    gemm_bf16<64, 0><<<g512, blk, 0, stream>>>(attnb, wtp[7], ca_ob, proj, nullptr, nullptr, 4096, 512, 512);
    add_ln<true, false, true><<<gln, blk, 0, stream>>>(x1b, proj, ln1_g, ln1_b, nullptr, x2b);

    // ---- feed-forward ----
    gemm_bf16<128, 3><<<gff1, blk, 0, stream>>>(x2b, wtp[8], ff_b1, nullptr, ffb, nullptr, 4096, 2048, 512);
    gemm_bf16<64, 0><<<g512, blk, 0, stream>>>(ffb, wtp[9], ff_b2, proj, nullptr, nullptr, 4096, 512, 2048);
    add_ln<true, true, false><<<gln, blk, 0, stream>>>(x2b, proj, ln2_g, ln2_b, out, nullptr);
}

// Round 4
// 249.361 us; speedup vs baseline: 6.0412x; 1.1950x over previous
//
#include <hip/hip_runtime.h>
#include <math.h>

// ---------------------------------------------------------------------------
// Decoder block: B=2, S=2048, D=512, H=8, DK=64, FF=2048.
// bf16 MFMA everywhere; QK^T bf16x3 split preserves floor(qk/8).
// Round 4: double-buffered prefetch (1 barrier/tile), merged QKV launch,
// XCD-chunked block swizzle.
// LDS tiles: [rows][64] bf16, XOR-16B swizzle (phys_short = col ^ ((row&7)*8)),
// staged via global_load_lds with inverse-swizzled global source.
// ---------------------------------------------------------------------------

typedef __attribute__((ext_vector_type(8))) short short8;   // 8 bf16
typedef __attribute__((ext_vector_type(4))) float f32x4;

#define MFMA16(a, b, c) __builtin_amdgcn_mfma_f32_16x16x32_bf16((a), (b), (c), 0, 0, 0)

__device__ __forceinline__ unsigned short f2bf(float f) {
    unsigned int u = __float_as_uint(f);
    u += 0x7fffu + ((u >> 16) & 1u);          // RNE
    return (unsigned short)(u >> 16);
}
__device__ __forceinline__ float bf2f(unsigned short h) {
    return __uint_as_float(((unsigned int)h) << 16);
}
__device__ __forceinline__ void g2l16(const void* g, void* l) {
    __builtin_amdgcn_global_load_lds(
        (const __attribute__((address_space(1))) unsigned int*)g,
        (__attribute__((address_space(3))) unsigned int*)l, 16, 0, 0);
}
// swizzled short-index within a [rows][64]-short LDS tile
__device__ __forceinline__ int swz(int row, int col) {
    return row * 64 + (col ^ ((row & 7) * 8));
}
// XCD-chunked work remap: block at linear id L computes work chunk
// (L%8)*cpx + L/8 so each XCD gets a contiguous work range. All grids %8==0.
__device__ __forceinline__ void xcd_remap(int& bx, int& by, int& bz) {
    const int gx = gridDim.x, gy = gridDim.y;
    const int nwg = gx * gy * gridDim.z;
    const int flat = blockIdx.x + gx * (blockIdx.y + gy * blockIdx.z);
    const int s = (flat & 7) * (nwg >> 3) + (flat >> 3);
    bx = s % gx; const int t = s / gx; by = t % gy; bz = t / gy;
}

// ---------------- bf16 GEMM: C[M,N] = A[M,K] @ Bt[N,K]^T + bias ------------
// BM=128, BK=64, 4 waves, double-buffered. MODE: 0 = f32 out;
// 2 = transposed bf16 out Vt[b][h][d][key]; 3 = bf16 out + ReLU.
template <int BN, int MODE>
__global__ __launch_bounds__(256, BN == 128 ? 2 : 3) void gemm_bf16(
    const unsigned short* __restrict__ A, const unsigned short* __restrict__ Bt,
    const float* __restrict__ bias, float* __restrict__ Cf,
    unsigned short* __restrict__ O1,
    int M, int N, int K)
{
    __shared__ unsigned short As[2][128 * 64];
    __shared__ unsigned short Bs[2][BN * 64];
    const int tid = threadIdx.x, wv = tid >> 6, lane = tid & 63;
    const int l15 = lane & 15, l4 = lane >> 4;
    int bx, by, bz; xcd_remap(bx, by, bz);
    const int bm = by * 128, bn = bx * BN;
    constexpr int MI = (BN == 128) ? 4 : 2;
    const int wrow = (BN == 128) ? ((wv >> 1) * 64) : (wv * 32);
    const int wcol = (BN == 128) ? ((wv & 1) * 64) : 0;

    f32x4 acc[MI][4];
    #pragma unroll
    for (int i = 0; i < MI; ++i)
        #pragma unroll
        for (int j = 0; j < 4; ++j) acc[i][j] = (f32x4){0.f, 0.f, 0.f, 0.f};

    const int srow = lane >> 3;                       // 0..7 within 8-row chunk
    const int sch  = (lane & 7) ^ srow;               // inverse-swizzled 16B chunk
    const unsigned short* Asrc = A + (size_t)(bm + wv * 32 + srow) * K + sch * 8;
    const unsigned short* Bsrc = Bt + (size_t)(bn + ((BN == 128) ? wv * 32 : wv * 16) + srow) * K + sch * 8;

    auto stage = [&](int buf, int k0) {
        #pragma unroll
        for (int j = 0; j < 4; ++j)
            g2l16(Asrc + (size_t)j * 8 * K + k0, &As[buf][(wv * 32 + j * 8) * 64]);
        #pragma unroll
        for (int j = 0; j < (BN == 128 ? 4 : 2); ++j)
            g2l16(Bsrc + (size_t)j * 8 * K + k0,
                  &Bs[buf][((BN == 128 ? wv * 32 : wv * 16) + j * 8) * 64]);
    };

    stage(0, 0);
    __syncthreads();
    int cur = 0;
    for (int k0 = 0; k0 < K; k0 += 64) {
        if (k0 + 64 < K) stage(cur ^ 1, k0 + 64);
        #pragma unroll
        for (int kk = 0; kk < 2; ++kk) {
            const int kc = kk * 32 + l4 * 8;
            short8 af[MI], bfr[4];
            #pragma unroll
            for (int mi = 0; mi < MI; ++mi)
                af[mi] = *(const short8*)&As[cur][swz(wrow + mi * 16 + l15, kc)];
            #pragma unroll
            for (int nf = 0; nf < 4; ++nf)
                bfr[nf] = *(const short8*)&Bs[cur][swz(wcol + nf * 16 + l15, kc)];
            __builtin_amdgcn_s_setprio(1);
            #pragma unroll
            for (int mi = 0; mi < MI; ++mi)
                #pragma unroll
                for (int nf = 0; nf < 4; ++nf)
                    acc[mi][nf] = MFMA16(af[mi], bfr[nf], acc[mi][nf]);
            __builtin_amdgcn_s_setprio(0);
        }
        __syncthreads();
        cur ^= 1;
    }

    // epilogue: C col = l15-block, row = l4*4 + reg
    #pragma unroll
    for (int nf = 0; nf < 4; ++nf) {
        const int n = bn + wcol + nf * 16 + l15;
        const float bv = bias[n];
        #pragma unroll
        for (int mi = 0; mi < MI; ++mi) {
            const int m0 = bm + wrow + mi * 16 + l4 * 4;
            if (MODE == 2) {
                ushort4 pk;
                pk.x = f2bf(acc[mi][nf][0] + bv);
                pk.y = f2bf(acc[mi][nf][1] + bv);
                pk.z = f2bf(acc[mi][nf][2] + bv);
                pk.w = f2bf(acc[mi][nf][3] + bv);
                const int hh = n >> 6, dd = n & 63, bb = m0 >> 11, key = m0 & 2047;
                *(ushort4*)(O1 + ((((size_t)bb * 8 + hh) * 64 + dd) * 2048 + key)) = pk;
            } else {
                #pragma unroll
                for (int r = 0; r < 4; ++r) {
                    float v = acc[mi][nf][r] + bv;
                    size_t idx = (size_t)(m0 + r) * N + n;
                    if (MODE == 0) Cf[idx] = v;
                    else           O1[idx] = f2bf(fmaxf(v, 0.f));   // MODE 3
                }
            }
        }
    }
}

// ---------------- merged QKV GEMM (3 jobs in one launch) -------------------
// grid (8, 32, 3); BM=128, BN=64, M=4096, N=512, K=512.
// mode 1 = hi/lo bf16 dual out; mode 2 = transposed Vt out.
struct QKVArgs {
    const unsigned short* A[3];
    const unsigned short* Bt[3];
    const float* bias[3];
    unsigned short* O1[3];
    unsigned short* O2[3];
    int mode[3];
};
__global__ __launch_bounds__(256, 3) void qkv_gemm(QKVArgs ja)
{
    __shared__ unsigned short As[2][128 * 64];
    __shared__ unsigned short Bs[2][64 * 64];
    const int tid = threadIdx.x, wv = tid >> 6, lane = tid & 63;
    const int l15 = lane & 15, l4 = lane >> 4;
    int bx, by, bz; xcd_remap(bx, by, bz);
    const int bm = by * 128, bn = bx * 64;
    const unsigned short* A  = ja.A[bz];
    const unsigned short* Bt = ja.Bt[bz];
    const int mode = ja.mode[bz];

    f32x4 acc[2][4];
    #pragma unroll
    for (int i = 0; i < 2; ++i)
        #pragma unroll
        for (int j = 0; j < 4; ++j) acc[i][j] = (f32x4){0.f, 0.f, 0.f, 0.f};

    const int srow = lane >> 3, sch = (lane & 7) ^ srow;
    const unsigned short* Asrc = A + (size_t)(bm + wv * 32 + srow) * 512 + sch * 8;
    const unsigned short* Bsrc = Bt + (size_t)(bn + wv * 16 + srow) * 512 + sch * 8;

    auto stage = [&](int buf, int k0) {
        #pragma unroll
        for (int j = 0; j < 4; ++j)
            g2l16(Asrc + (size_t)j * 8 * 512 + k0, &As[buf][(wv * 32 + j * 8) * 64]);
        #pragma unroll
        for (int j = 0; j < 2; ++j)
            g2l16(Bsrc + (size_t)j * 8 * 512 + k0, &Bs[buf][(wv * 16 + j * 8) * 64]);
    };

    stage(0, 0);
    __syncthreads();
    int cur = 0;
    for (int k0 = 0; k0 < 512; k0 += 64) {
        if (k0 + 64 < 512) stage(cur ^ 1, k0 + 64);
        #pragma unroll
        for (int kk = 0; kk < 2; ++kk) {
            const int kc = kk * 32 + l4 * 8;
            short8 af[2], bfr[4];
            af[0] = *(const short8*)&As[cur][swz(wv * 32 + l15, kc)];
            af[1] = *(const short8*)&As[cur][swz(wv * 32 + 16 + l15, kc)];
            #pragma unroll
            for (int nf = 0; nf < 4; ++nf)
                bfr[nf] = *(const short8*)&Bs[cur][swz(nf * 16 + l15, kc)];
            __builtin_amdgcn_s_setprio(1);
            #pragma unroll
            for (int mi = 0; mi < 2; ++mi)
                #pragma unroll
                for (int nf = 0; nf < 4; ++nf)
                    acc[mi][nf] = MFMA16(af[mi], bfr[nf], acc[mi][nf]);
            __builtin_amdgcn_s_setprio(0);
        }
        __syncthreads();
        cur ^= 1;
    }

    #pragma unroll
    for (int nf = 0; nf < 4; ++nf) {
        const int n = bn + nf * 16 + l15;
        const float bv = ja.bias[bz][n];
        #pragma unroll
        for (int mi = 0; mi < 2; ++mi) {
            const int m0 = bm + wv * 32 + mi * 16 + l4 * 4;
            if (mode == 2) {
                ushort4 pk;
                pk.x = f2bf(acc[mi][nf][0] + bv);
                pk.y = f2bf(acc[mi][nf][1] + bv);
                pk.z = f2bf(acc[mi][nf][2] + bv);
                pk.w = f2bf(acc[mi][nf][3] + bv);
                const int hh = n >> 6, dd = n & 63, bb = m0 >> 11, key = m0 & 2047;
                *(ushort4*)(ja.O1[bz] + ((((size_t)bb * 8 + hh) * 64 + dd) * 2048 + key)) = pk;
            } else {
                #pragma unroll
                for (int r = 0; r < 4; ++r) {
                    float v = acc[mi][nf][r] + bv;
                    size_t idx = (size_t)(m0 + r) * 512 + n;
                    unsigned short hi = f2bf(v);
                    ja.O1[bz][idx] = hi;
                    ja.O2[bz][idx] = f2bf(v - bf2f(hi));
                }
            }
        }
    }
}

// ---------------- MFMA flash attention with floor(qk/8) --------------------
// Qh/Ql/Kh/Kl: [B*S, 512] bf16 head-major cols. Vt: [b][h][d][2048] bf16.
// Ob: [B*S, 512] bf16. Grid (S/64, B*H), block 256 (4 waves x 16 q-rows).
__global__ __launch_bounds__(256, 2) void attn_mfma(
    const unsigned short* __restrict__ Qh, const unsigned short* __restrict__ Ql,
    const unsigned short* __restrict__ Kh, const unsigned short* __restrict__ Kl,
    const unsigned short* __restrict__ Vt, unsigned short* __restrict__ Ob)
{
    __shared__ unsigned short KH[2][64 * 64];
    __shared__ unsigned short KL[2][64 * 64];
    __shared__ unsigned short VT[2][64 * 64];   // [d][key]
    __shared__ unsigned short QH[64 * 64];      // Q-hi, then P scratch
    __shared__ unsigned short QL[64 * 64];

    const int tid = threadIdx.x, wv = tid >> 6, lane = tid & 63;
    const int l15 = lane & 15, l4 = lane >> 4;
    int bx, by, bz; xcd_remap(bx, by, bz);
    const int bh = by, b = bh >> 3, h = bh & 7;
    const int q0 = bx * 64;
    const int srow = lane >> 3;
    const int sch  = (lane & 7) ^ srow;

    const unsigned short* kh_src = Kh + (size_t)(b * 2048 + wv * 16 + srow) * 512 + h * 64 + sch * 8;
    const unsigned short* kl_src = Kl + (size_t)(b * 2048 + wv * 16 + srow) * 512 + h * 64 + sch * 8;
    const unsigned short* vt_src = Vt + (size_t)(bh * 64 + wv * 16 + srow) * 2048 + sch * 8;

    auto stageKV = [&](int buf, int kt) {
        const size_t k0 = (size_t)kt * 64;
        #pragma unroll
        for (int j = 0; j < 2; ++j) {
            g2l16(kh_src + (k0 + j * 8) * 512, &KH[buf][(wv * 16 + j * 8) * 64]);
            g2l16(kl_src + (k0 + j * 8) * 512, &KL[buf][(wv * 16 + j * 8) * 64]);
            g2l16(vt_src + k0 + (size_t)j * 8 * 2048, &VT[buf][(wv * 16 + j * 8) * 64]);
        }
    };

    // stage Q hi/lo + first K/V tile
    {
        const unsigned short* qh_src = Qh + (size_t)(b * 2048 + q0 + wv * 16 + srow) * 512 + h * 64 + sch * 8;
        const unsigned short* ql_src = Ql + (size_t)(b * 2048 + q0 + wv * 16 + srow) * 512 + h * 64 + sch * 8;
        #pragma unroll
        for (int j = 0; j < 2; ++j) {
            g2l16(qh_src + (size_t)j * 8 * 512, &QH[(wv * 16 + j * 8) * 64]);
            g2l16(ql_src + (size_t)j * 8 * 512, &QL[(wv * 16 + j * 8) * 64]);
        }
        stageKV(0, 0);
    }
    __syncthreads();
    short8 qh[2], ql[2];
    #pragma unroll
    for (int kk = 0; kk < 2; ++kk) {
        qh[kk] = *(const short8*)&QH[swz(wv * 16 + l15, kk * 32 + l4 * 8)];
        ql[kk] = *(const short8*)&QL[swz(wv * 16 + l15, kk * 32 + l4 * 8)];
    }

    f32x4 o[4], lacc;
    #pragma unroll
    for (int i = 0; i < 4; ++i) o[i] = (f32x4){0.f, 0.f, 0.f, 0.f};
    lacc = (f32x4){0.f, 0.f, 0.f, 0.f};
    float m[4] = {-INFINITY, -INFINITY, -INFINITY, -INFINITY};

    const short one_s = (short)(l15 == 0 ? 0x3F80 : 0);     // bf16 1.0 in col 0
    const short8 oneb = {one_s, one_s, one_s, one_s, one_s, one_s, one_s, one_s};

    int cur = 0;
    for (int kt = 0; kt < 32; ++kt) {
        if (kt + 1 < 32) stageKV(cur ^ 1, kt + 1);

        // QK^T (bf16x3): wave's 16 q-rows x 64 keys
        f32x4 s[4];
        __builtin_amdgcn_s_setprio(1);
        #pragma unroll
        for (int f = 0; f < 4; ++f) {
            s[f] = (f32x4){0.f, 0.f, 0.f, 0.f};
            #pragma unroll
            for (int kk = 0; kk < 2; ++kk) {
                const int kc = kk * 32 + l4 * 8;
                short8 kbh = *(const short8*)&KH[cur][swz(f * 16 + l15, kc)];
                short8 kbl = *(const short8*)&KL[cur][swz(f * 16 + l15, kc)];
                s[f] = MFMA16(ql[kk], kbh, s[f]);
                s[f] = MFMA16(qh[kk], kbl, s[f]);
                s[f] = MFMA16(qh[kk], kbh, s[f]);
            }
        }
        __builtin_amdgcn_s_setprio(0);

        // floor + row max (16-lane reduce); defer-max (THR=8, integer scores)
        float t[4][4], pmax[4];
        bool need = false;
        #pragma unroll
        for (int r = 0; r < 4; ++r) {
            t[0][r] = floorf(s[0][r] * 0.125f);
            t[1][r] = floorf(s[1][r] * 0.125f);
            t[2][r] = floorf(s[2][r] * 0.125f);
            t[3][r] = floorf(s[3][r] * 0.125f);
            float mx = fmaxf(fmaxf(t[0][r], t[1][r]), fmaxf(t[2][r], t[3][r]));
            mx = fmaxf(mx, __shfl_xor(mx, 1));
            mx = fmaxf(mx, __shfl_xor(mx, 2));
            mx = fmaxf(mx, __shfl_xor(mx, 4));
            mx = fmaxf(mx, __shfl_xor(mx, 8));
            pmax[r] = mx;
            need = need || (mx > m[r] + 8.f);
        }
        if (__any(need)) {
            #pragma unroll
            for (int r = 0; r < 4; ++r) {
                float mnew = fmaxf(m[r], pmax[r]);
                float corr = __expf(m[r] - mnew);    // -inf -> 0 first tile
                o[0][r] *= corr; o[1][r] *= corr; o[2][r] *= corr; o[3][r] *= corr;
                lacc[r] *= corr;
                m[r] = mnew;
            }
        }
        // P = exp(t - m) (bounded by e^8), bf16 into QH (wave-private rows)
        #pragma unroll
        for (int f = 0; f < 4; ++f)
            #pragma unroll
            for (int r = 0; r < 4; ++r)
                QH[swz(wv * 16 + l4 * 4 + r, f * 16 + l15)] = f2bf(__expf(t[f][r] - m[r]));

        short8 pa[2];
        pa[0] = *(const short8*)&QH[swz(wv * 16 + l15, l4 * 8)];
        pa[1] = *(const short8*)&QH[swz(wv * 16 + l15, 32 + l4 * 8)];

        __builtin_amdgcn_s_setprio(1);
        lacc = MFMA16(pa[0], oneb, lacc);     // row-sum via ones column
        lacc = MFMA16(pa[1], oneb, lacc);
        #pragma unroll
        for (int df = 0; df < 4; ++df) {
            #pragma unroll
            for (int kk = 0; kk < 2; ++kk) {
                short8 vb = *(const short8*)&VT[cur][swz(df * 16 + l15, kk * 32 + l4 * 8)];
                o[df] = MFMA16(pa[kk], vb, o[df]);
            }
        }
        __builtin_amdgcn_s_setprio(0);
        __syncthreads();
        cur ^= 1;
    }

    // epilogue: l lives in lanes l15==0 (col 0 of lacc); broadcast + store bf16
    float linv[4];
    #pragma unroll
    for (int r = 0; r < 4; ++r) linv[r] = 1.f / __shfl(lacc[r], lane & 48);
    #pragma unroll
    for (int df = 0; df < 4; ++df)
        #pragma unroll
        for (int r = 0; r < 4; ++r) {
            size_t idx = (size_t)(b * 2048 + q0 + wv * 16 + l4 * 4 + r) * 512 + h * 64 + df * 16 + l15;
            Ob[idx] = f2bf(o[df][r] * linv[r]);
        }
}

// ---------------- fused residual add + LayerNorm (D=512) -------------------
template <bool XBF, bool OUTF, bool OUTB>
__global__ __launch_bounds__(256) void add_ln(
    const void* __restrict__ Xv, const float* __restrict__ R,
    const float* __restrict__ g, const float* __restrict__ beta,
    float* __restrict__ OutF, unsigned short* __restrict__ OutB)
{
    const int row = blockIdx.x * 4 + (threadIdx.x >> 6);
    const int lane = threadIdx.x & 63;
    const int c0 = lane * 8;
    float v[8];
    const float* rr = R + (size_t)row * 512 + c0;
    float4 r0 = *(const float4*)rr, r1 = *(const float4*)(rr + 4);
    float xx[8];
    if (XBF) {
        const unsigned short* xr = (const unsigned short*)Xv + (size_t)row * 512 + c0;
        uint4 u = *(const uint4*)xr;
        xx[0] = bf2f(u.x & 0xffff); xx[1] = bf2f(u.x >> 16);
        xx[2] = bf2f(u.y & 0xffff); xx[3] = bf2f(u.y >> 16);
        xx[4] = bf2f(u.z & 0xffff); xx[5] = bf2f(u.z >> 16);
        xx[6] = bf2f(u.w & 0xffff); xx[7] = bf2f(u.w >> 16);
    } else {
        const float* xr = (const float*)Xv + (size_t)row * 512 + c0;
        float4 a0 = *(const float4*)xr, a1 = *(const float4*)(xr + 4);
        xx[0] = a0.x; xx[1] = a0.y; xx[2] = a0.z; xx[3] = a0.w;
        xx[4] = a1.x; xx[5] = a1.y; xx[6] = a1.z; xx[7] = a1.w;
    }
    v[0] = xx[0] + r0.x; v[1] = xx[1] + r0.y; v[2] = xx[2] + r0.z; v[3] = xx[3] + r0.w;
    v[4] = xx[4] + r1.x; v[5] = xx[5] + r1.y; v[6] = xx[6] + r1.z; v[7] = xx[7] + r1.w;
    float s = 0.f, s2 = 0.f;
    #pragma unroll
    for (int j = 0; j < 8; ++j) { s += v[j]; s2 += v[j] * v[j]; }
    #pragma unroll
    for (int off = 1; off < 64; off <<= 1) {
        s  += __shfl_xor(s, off);
        s2 += __shfl_xor(s2, off);
    }
    const float mean = s * (1.f / 512.f);
    const float var = s2 * (1.f / 512.f) - mean * mean;
    const float rs = 1.f / sqrtf(var + 1e-5f);
    float ovals[8];
    const float* gg = g + c0; const float* bb = beta + c0;
    #pragma unroll
    for (int j = 0; j < 8; ++j) ovals[j] = (v[j] - mean) * rs * gg[j] + bb[j];
    if (OUTF) {
        float* po = OutF + (size_t)row * 512 + c0;
        *(float4*)po = (float4){ovals[0], ovals[1], ovals[2], ovals[3]};
        *(float4*)(po + 4) = (float4){ovals[4], ovals[5], ovals[6], ovals[7]};
    }
    if (OUTB) {
        uint4 u;
        u.x = (unsigned)f2bf(ovals[0]) | ((unsigned)f2bf(ovals[1]) << 16);
        u.y = (unsigned)f2bf(ovals[2]) | ((unsigned)f2bf(ovals[3]) << 16);
        u.z = (unsigned)f2bf(ovals[4]) | ((unsigned)f2bf(ovals[5]) << 16);
        u.w = (unsigned)f2bf(ovals[6]) | ((unsigned)f2bf(ovals[7]) << 16);
        *(uint4*)(OutB + (size_t)row * 512 + c0) = u;
    }
}

// ---------------- f32 -> bf16 convert for x and enc ------------------------
__global__ __launch_bounds__(256) void conv_bf16(
    const float* __restrict__ X, const float* __restrict__ E,
    unsigned short* __restrict__ Xb, unsigned short* __restrict__ Eb)
{
    size_t i = ((size_t)blockIdx.x * 256 + threadIdx.x) * 8;
    const float* src; unsigned short* dst; size_t off;
    if (i < 2097152) { src = X; dst = Xb; off = i; }
    else             { src = E; dst = Eb; off = i - 2097152; }
    float4 a = *(const float4*)(src + off), c = *(const float4*)(src + off + 4);
    uint4 u;
    u.x = (unsigned)f2bf(a.x) | ((unsigned)f2bf(a.y) << 16);
    u.y = (unsigned)f2bf(a.z) | ((unsigned)f2bf(a.w) << 16);
    u.z = (unsigned)f2bf(c.x) | ((unsigned)f2bf(c.y) << 16);
    u.w = (unsigned)f2bf(c.z) | ((unsigned)f2bf(c.w) << 16);
    *(uint4*)(dst + off) = u;
}

// ---------------- batched weight transpose+convert: [K][N] f32 -> [N][K] bf16
struct WTJobs {
    const float* src[10];
    unsigned short* dst[10];
    int K[10], N[10];
    int cum[11];
};
__global__ __launch_bounds__(256) void wtrans(WTJobs jb)
{
    int bid = blockIdx.x;
    int z = 0;
    while (bid >= jb.cum[z + 1]) ++z;
    const int lt = bid - jb.cum[z];
    const int K = jb.K[z], N = jb.N[z];
    const int ntx = N >> 5;
    const int tx = lt % ntx, ty = lt / ntx;
    __shared__ float T[32][33];
    const int r = threadIdx.x >> 3, c4 = (threadIdx.x & 7) * 4;
    float4 a = *(const float4*)(jb.src[z] + (size_t)(ty * 32 + r) * N + tx * 32 + c4);
    T[r][c4] = a.x; T[r][c4 + 1] = a.y; T[r][c4 + 2] = a.z; T[r][c4 + 3] = a.w;
    __syncthreads();
    ushort4 o;
    o.x = f2bf(T[c4][r]); o.y = f2bf(T[c4 + 1][r]);
    o.z = f2bf(T[c4 + 2][r]); o.w = f2bf(T[c4 + 3][r]);
    *(ushort4*)(jb.dst[z] + (size_t)(tx * 32 + r) * K + ty * 32 + c4) = o;
}

// ---------------------------------------------------------------------------
extern "C" void kernel_launch(void* const* d_in, const int* in_sizes, int n_in,
                              void* d_out, int out_size, void* d_ws, size_t ws_size,
                              hipStream_t stream)
{
    const float* x   = (const float*)d_in[0];
    const float* enc = (const float*)d_in[1];
    // d_in[2], d_in[3]: masks — dead in the reference.
    const float* Wp[8] = {(const float*)d_in[4],  (const float*)d_in[6],
                          (const float*)d_in[8],  (const float*)d_in[10],
                          (const float*)d_in[12], (const float*)d_in[14],
                          (const float*)d_in[16], (const float*)d_in[18]};
    const float* sa_qb = (const float*)d_in[5],  *sa_kb = (const float*)d_in[7];
    const float* sa_vb = (const float*)d_in[9],  *sa_ob = (const float*)d_in[11];
    const float* ca_qb = (const float*)d_in[13], *ca_kb = (const float*)d_in[15];
    const float* ca_vb = (const float*)d_in[17], *ca_ob = (const float*)d_in[19];
    const float* ff_W1 = (const float*)d_in[20], *ff_b1 = (const float*)d_in[21];
    const float* ff_W2 = (const float*)d_in[22], *ff_b2 = (const float*)d_in[23];
    const float* ln0_g = (const float*)d_in[24], *ln0_b = (const float*)d_in[25];
    const float* ln1_g = (const float*)d_in[26], *ln1_b = (const float*)d_in[27];
    const float* ln2_g = (const float*)d_in[28], *ln2_b = (const float*)d_in[29];

    char* base = (char*)d_ws;
    const size_t MB = 1u << 20;
    unsigned short* wt   = (unsigned short*)(base + 0 * MB);   // 8 MB
    unsigned short* xb   = (unsigned short*)(base + 8 * MB);   // 4 MB (reused as x2b)
    unsigned short* encb = (unsigned short*)(base + 12 * MB);  // 4 MB
    unsigned short* x1b  = (unsigned short*)(base + 16 * MB);  // 4 MB
    unsigned short* attnb= (unsigned short*)(base + 20 * MB);  // 4 MB
    unsigned short* vt   = (unsigned short*)(base + 24 * MB);  // 4 MB
    unsigned short* qhi  = (unsigned short*)(base + 28 * MB);  // 4 MB each
    unsigned short* qlo  = (unsigned short*)(base + 32 * MB);
    unsigned short* khi  = (unsigned short*)(base + 36 * MB);
    unsigned short* klo  = (unsigned short*)(base + 40 * MB);
    unsigned short* ffb  = qhi;                                // 16 MB overlay
    unsigned short* x2b  = xb;                                 // overlay
    float* proj = (float*)(base + 44 * MB);                    // 8 MB
    float* out  = (float*)d_out;

    unsigned short* wtp[10];
    for (int i = 0; i < 8; ++i) wtp[i] = wt + (size_t)i * 262144;
    wtp[8] = wt + 8u * 262144;            // ff_W1t: [2048][512]
    wtp[9] = wt + 8u * 262144 + 1048576;  // ff_W2t: [512][2048]

    WTJobs jb;
    for (int i = 0; i < 8; ++i) { jb.src[i] = Wp[i]; jb.dst[i] = wtp[i]; jb.K[i] = 512; jb.N[i] = 512; }
    jb.src[8] = ff_W1; jb.dst[8] = wtp[8]; jb.K[8] = 512;  jb.N[8] = 2048;
    jb.src[9] = ff_W2; jb.dst[9] = wtp[9]; jb.K[9] = 2048; jb.N[9] = 512;
    jb.cum[0] = 0;
    for (int i = 0; i < 10; ++i)
        jb.cum[i + 1] = jb.cum[i] + (jb.N[i] >> 5) * (jb.K[i] >> 5);

    QKVArgs sa, ca;
    for (int z = 0; z < 3; ++z) { sa.A[z] = xb; sa.O2[z] = nullptr; ca.O2[z] = nullptr; }
    sa.Bt[0] = wtp[0]; sa.bias[0] = sa_qb; sa.O1[0] = qhi; sa.O2[0] = qlo; sa.mode[0] = 1;
    sa.Bt[1] = wtp[1]; sa.bias[1] = sa_kb; sa.O1[1] = khi; sa.O2[1] = klo; sa.mode[1] = 1;
    sa.Bt[2] = wtp[2]; sa.bias[2] = sa_vb; sa.O1[2] = vt;                  sa.mode[2] = 2;
    ca.A[0] = x1b;  ca.Bt[0] = wtp[4]; ca.bias[0] = ca_qb; ca.O1[0] = qhi; ca.O2[0] = qlo; ca.mode[0] = 1;
    ca.A[1] = encb; ca.Bt[1] = wtp[5]; ca.bias[1] = ca_kb; ca.O1[1] = khi; ca.O2[1] = klo; ca.mode[1] = 1;
    ca.A[2] = encb; ca.Bt[2] = wtp[6]; ca.bias[2] = ca_vb; ca.O1[2] = vt;                  ca.mode[2] = 2;

    dim3 blk(256);
    dim3 gqkv(8, 32, 3);
    dim3 g512(8, 32);
    dim3 gff1(16, 32);
    dim3 gattn(32, 16);
    dim3 gln(1024);

    conv_bf16<<<2048, blk, 0, stream>>>(x, enc, xb, encb);
    wtrans<<<jb.cum[10], blk, 0, stream>>>(jb);

    // ---- self-attention ----
    qkv_gemm<<<gqkv, blk, 0, stream>>>(sa);
    attn_mfma<<<gattn, blk, 0, stream>>>(qhi, qlo, khi, klo, vt, attnb);
    gemm_bf16<64, 0><<<g512, blk, 0, stream>>>(attnb, wtp[3], sa_ob, proj, nullptr, 4096, 512, 512);
    add_ln<false, false, true><<<gln, blk, 0, stream>>>(x, proj, ln0_g, ln0_b, nullptr, x1b);

    // ---- cross-attention ----
    qkv_gemm<<<gqkv, blk, 0, stream>>>(ca);
    attn_mfma<<<gattn, blk, 0, stream>>>(qhi, qlo, khi, klo, vt, attnb);
    gemm_bf16<64, 0><<<g512, blk, 0, stream>>>(attnb, wtp[7], ca_ob, proj, nullptr, 4096, 512, 512);
    add_ln<true, false, true><<<gln, blk, 0, stream>>>(x1b, proj, ln1_g, ln1_b, nullptr, x2b);

    // ---- feed-forward ----
    gemm_bf16<128, 3><<<gff1, blk, 0, stream>>>(x2b, wtp[8], ff_b1, nullptr, ffb, 4096, 2048, 512);
    gemm_bf16<64, 0><<<g512, blk, 0, stream>>>(ffb, wtp[9], ff_b2, proj, nullptr, 4096, 512, 2048);
    add_ln<true, true, false><<<gln, blk, 0, stream>>>(x2b, proj, ln2_g, ln2_b, out, nullptr);
}